// Round 10
// baseline (209.673 us; speedup 1.0000x reference)
//
#include <hip/hip_runtime.h>
#include <cstddef>

#define B_ 4
#define C_ 512
#define L_ 2048

typedef __attribute__((ext_vector_type(8))) short  short8;   // 8 bf16 (4 VGPRs)
typedef __attribute__((ext_vector_type(4))) float  f32x4;
typedef __attribute__((ext_vector_type(4))) unsigned short us4;

#define AS1 __attribute__((address_space(1)))
#define AS3 __attribute__((address_space(3)))

__device__ __forceinline__ float clip10(float v){ return fminf(fmaxf(v,-10.0f),10.0f); }

// round-to-nearest-even fp32 -> bf16 (finite inputs only; ours are clipped)
__device__ __forceinline__ unsigned short f2bf(float f){
  union { float f; unsigned u; } v; v.f = f;
  unsigned r = v.u + 0x7fffu + ((v.u >> 16) & 1u);
  return (unsigned short)(r >> 16);
}
// truncation-pack two fp32 -> bf16x2 in ONE v_perm_b32 (lo -> low half)
__device__ __forceinline__ unsigned pk_tr(float lo, float hi){
  return __builtin_amdgcn_perm(__float_as_uint(hi), __float_as_uint(lo), 0x07060302u);
}
__device__ __forceinline__ float bf2f(unsigned short u){
  return __uint_as_float(((unsigned)u)<<16);
}
// async 16B global -> LDS (direct-to-shared DMA)
__device__ __forceinline__ void gl16(const void* g, void* l){
  __builtin_amdgcn_global_load_lds((const AS1 unsigned*)g, (AS3 unsigned*)l, 16, 0, 0);
}

// ---------------------------------------------------------------------------
// Prep: blocks 0..4095 transpose x -> xT bf16; 4096..5119 convert W;
// block 5120 zeroes the groupnorm partial accumulators (re-poison-safe).
// ---------------------------------------------------------------------------
__global__ __launch_bounds__(256) void prep_k(
    const float* __restrict__ x, const float* __restrict__ Wq,
    const float* __restrict__ Wp, unsigned short* __restrict__ xT,
    unsigned short* __restrict__ Wqb, unsigned short* __restrict__ Wpb,
    float* __restrict__ part)
{
  const int blk = blockIdx.x;
  const int t = threadIdx.x;
  if (blk < 4096){
    __shared__ float tile[32][33];
    const int b = blk>>10, rem = blk&1023;
    const int c0 = (rem>>6)*32, l0 = (rem&63)*32;
    const int cr = t>>3, lc = (t&7)*4;
    const float4 v = *(const float4*)(x + ((size_t)b*C_ + c0+cr)*L_ + l0 + lc);
    tile[cr][lc]=v.x; tile[cr][lc+1]=v.y; tile[cr][lc+2]=v.z; tile[cr][lc+3]=v.w;
    __syncthreads();
    const int lr = t>>3, cc = (t&7)*4;
    const us4 o = { f2bf(tile[cc][lr]), f2bf(tile[cc+1][lr]),
                    f2bf(tile[cc+2][lr]), f2bf(tile[cc+3][lr]) };
    *(us4*)(xT + ((size_t)b*L_ + l0+lr)*C_ + c0 + cc) = o;
  } else if (blk < 5120){
    const int i = (blk-4096)*256 + t;       // float4 index
    const int NQ = 1536*512/4;
    const float* src; unsigned short* dst; int j;
    if (i < NQ){ src = Wq; dst = Wqb; j = i; }
    else       { src = Wp; dst = Wpb; j = i - NQ; }
    const float4 v = *(const float4*)(src + (size_t)j*4);
    const us4 o = { f2bf(v.x), f2bf(v.y), f2bf(v.z), f2bf(v.w) };
    *(us4*)(dst + (size_t)j*4) = o;
  } else {
    part[t] = 0.f;                          // 4 batches x 32 groups x {sum,sq}
  }
}

// ---------------------------------------------------------------------------
// bf16 MFMA GEMM (LDS-DMA), 128x128 tile, BK=64, K=512.
// LDS chunks XOR-swizzled: physical chunk = logical ^ (row&7).
// MODE 0 (QKV): +bias, clip; q scaled by 0.125*log2e; q/k bf16 [b][l][512];
//               v bf16 [b][512][l]. For v-blocks (mb>=8) the MFMA operands
//               are SWAPPED (D^T computed) so v stores become 8B us4 along l.
// MODE 1 (proj): +bias +x residual -> y fp32 [b][512][l]; per-group (16ch)
//               sum/sumsq wave-reduced and atomicAdd'ed into part[b][g].
// ---------------------------------------------------------------------------
template<int MODE>
__global__ __launch_bounds__(256) void mfma_gemm(
    const unsigned short* __restrict__ Wb, const unsigned short* __restrict__ Bin,
    const float* __restrict__ bias, const float* __restrict__ xres,
    unsigned short* __restrict__ qT, unsigned short* __restrict__ kT,
    unsigned short* __restrict__ vN, float* __restrict__ yout,
    float* __restrict__ part)
{
  __shared__ unsigned short SA[128*64];   // [m][k'] bf16, 16KB
  __shared__ unsigned short SB[128*64];   // [n][k'] bf16, 16KB
  const int t = threadIdx.x;
  const int b = blockIdx.z;
  const int mb = blockIdx.y, n0 = blockIdx.x*128, m0 = mb*128;
  const int lane = t&63, w = t>>6, wm = w>>1, wn = w&1;
  const int n = lane&15, q4 = lane>>4;
  const bool VSWAP = (MODE==0) && (mb>=8);

  f32x4 acc[4][4];
#pragma unroll
  for (int i=0;i<4;i++)
#pragma unroll
    for (int j=0;j<4;j++) acc[i][j] = (f32x4){0.f,0.f,0.f,0.f};

  const unsigned short* Arow = Wb + (size_t)m0*512;
  const unsigned short* Brow = Bin + ((size_t)b*L_ + n0)*512;

  for (int kt=0; kt<8; kt++){
    const int k0 = kt*64;
    __syncthreads();                     // prev-iter fragment reads done
#pragma unroll
    for (int i=0;i<4;i++){
      const int ch = t + 256*i;          // 0..1023 : row=ch>>3, phys chunk=ch&7
      const int row = ch>>3, lc = (ch&7) ^ (row&7);
      gl16(Arow + (size_t)row*512 + k0 + lc*8, &SA[ch*8]);
      gl16(Brow + (size_t)row*512 + k0 + lc*8, &SB[ch*8]);
    }
    __syncthreads();                     // vmcnt(0) drained by compiler
#pragma unroll
    for (int kk=0;kk<2;kk++){
      short8 aF[4], bF[4];
      const int pc = ((kk*4+q4) ^ (n&7))*8;
#pragma unroll
      for (int mt=0;mt<4;mt++) aF[mt] = *(const short8*)&SA[(wm*64+mt*16+n)*64 + pc];
#pragma unroll
      for (int nt=0;nt<4;nt++) bF[nt] = *(const short8*)&SB[(wn*64+nt*16+n)*64 + pc];
      if (VSWAP){
#pragma unroll
        for (int mt=0;mt<4;mt++)
#pragma unroll
          for (int nt=0;nt<4;nt++)
            acc[mt][nt] = __builtin_amdgcn_mfma_f32_16x16x32_bf16(bF[nt], aF[mt], acc[mt][nt], 0,0,0);
      } else {
#pragma unroll
        for (int mt=0;mt<4;mt++)
#pragma unroll
          for (int nt=0;nt<4;nt++)
            acc[mt][nt] = __builtin_amdgcn_mfma_f32_16x16x32_bf16(aF[mt], bF[nt], acc[mt][nt], 0,0,0);
      }
    }
  }

  const float QS = 0.180336880f;   // 0.125 * log2(e), folded into q
  if (VSWAP){
    // D^T: acc[mt][nt][r] = value at l = n0+wn*64+nt*16+q4*4+r,
    //                       c = m0+wm*64+mt*16+n  (channel 1024..1535)
#pragma unroll
    for (int mt=0;mt<4;mt++){
      const int o = m0 + wm*64 + mt*16 + n;
      const float bv = bias[o];
#pragma unroll
      for (int nt=0;nt<4;nt++){
        const int l = n0 + wn*64 + nt*16 + q4*4;
        const float r0=clip10(acc[mt][nt][0]+bv), r1=clip10(acc[mt][nt][1]+bv),
                    r2=clip10(acc[mt][nt][2]+bv), r3=clip10(acc[mt][nt][3]+bv);
        const us4 ov = { f2bf(r0), f2bf(r1), f2bf(r2), f2bf(r3) };
        *(us4*)&vN[((size_t)b*512 + (o-1024))*L_ + l] = ov;   // 8B store along l
      }
    }
    return;
  }
  // ---- normal epilogue: C row = m (quad*4+reg), col = n (lane&15)
#pragma unroll
  for (int mt=0;mt<4;mt++){
    const int obase = m0 + wm*64 + mt*16 + q4*4;
    const float b0=bias[obase], b1=bias[obase+1], b2=bias[obase+2], b3=bias[obase+3];
    float gs=0.f, gq=0.f;
#pragma unroll
    for (int nt=0;nt<4;nt++){
      const int l = n0 + wn*64 + nt*16 + n;
      float r0=acc[mt][nt][0]+b0, r1=acc[mt][nt][1]+b1,
            r2=acc[mt][nt][2]+b2, r3=acc[mt][nt][3]+b3;
      if (MODE==0){
        r0=clip10(r0); r1=clip10(r1); r2=clip10(r2); r3=clip10(r3);
        const int typ = mb>>2;                     // 0=q 1=k (v handled above)
        const int oin = obase - typ*512;
        if (typ==0){ r0*=QS; r1*=QS; r2*=QS; r3*=QS; }
        unsigned short* dst = (typ==0) ? qT : kT;
        const us4 o = { f2bf(r0), f2bf(r1), f2bf(r2), f2bf(r3) };
        *(us4*)&dst[((size_t)b*L_ + l)*512 + oin] = o;   // [l][c], 8B store
      } else {
        const float* xp = xres + ((size_t)b*512 + obase)*L_ + l;
        const float y0=r0+xp[0], y1=r1+xp[(size_t)L_],
                    y2=r2+xp[(size_t)2*L_], y3=r3+xp[(size_t)3*L_];
        float* dst = yout + ((size_t)b*512 + obase)*L_ + l;
        dst[0]=y0; dst[(size_t)L_]=y1; dst[(size_t)2*L_]=y2; dst[(size_t)3*L_]=y3;
        gs += (y0+y1)+(y2+y3);
        gq += (y0*y0+y1*y1)+(y2*y2+y3*y3);
      }
    }
    if (MODE==1){
      // whole wave belongs to one 16-channel group for this mt
#pragma unroll
      for (int off=1; off<64; off<<=1){
        gs += __shfl_xor(gs, off);
        gq += __shfl_xor(gq, off);
      }
      if (lane==0){
        const int g = mb*8 + wm*4 + mt;
        atomicAdd(&part[(b*32+g)*2+0], gs);
        atomicAdd(&part[(b*32+g)*2+1], gq);
      }
    }
  }
}

// ---------------------------------------------------------------------------
// MFMA attention v12: 128-i tile, j-split x2 across blocks (grid 1024) AND
// wave-level split of each staged 64-j tile: wave (wi,wj) handles i-half wi
// (64 i, mt 0..3) x j-half wj (32 j). Each wave reads only its quarter of
// the K/V fragments (12 b128/iter vs 20) serving 2x the i*j work per read.
// O/den cross-wave (wj) partials summed through LDS at epilogue.
// den via ones-column MFMA. Outputs unnormalized bf16 O + fp32 den partials.
// ---------------------------------------------------------------------------
#define PP 72   // s_p pitch in bf16: 144B rows, 16B-aligned, 2-way banks max
#define EXP 66  // fp32 exchange row pitch (<=2-way banks)

__global__ __launch_bounds__(256,3) void attn_v12(
    const unsigned short* __restrict__ qT, const unsigned short* __restrict__ kT,
    const unsigned short* __restrict__ vN,
    unsigned short* __restrict__ Opart, float* __restrict__ den)
{
  __shared__ unsigned short smem[2*64*64 + 128*PP];   // s_k | s_v | s_p, 34816B
  unsigned short* s_k = smem;
  unsigned short* s_v = smem + 4096;
  unsigned short* s_p = smem + 8192;
  const int t  = threadIdx.x;
  const int io = blockIdx.x>>1, half = blockIdx.x&1;
  const int i0 = io*128;
  const int h  = blockIdx.y, b = blockIdx.z;
  const int lane = t&63, w = t>>6, n = lane&15, q4 = lane>>4;
  const int wi = w&1, wj = w>>1;
  const int idx = ((b*8+h)*16+io)*2 + half;

  const unsigned short* kb0 = kT + (size_t)b*L_*512 + h*64;
  const unsigned short* vb  = vN + ((size_t)b*512 + h*64)*L_;

  // ---- Q B-fragments (rows i = i0 + wi*64 + mt*16 + n), hoisted once
  short8 qf[4][2];
#pragma unroll
  for (int mt=0; mt<4; mt++)
#pragma unroll
    for (int kk=0; kk<2; kk++)
      qf[mt][kk] = *(const short8*)(qT + ((size_t)b*L_ + i0 + wi*64 + mt*16 + n)*512
                                       + h*64 + kk*32 + q4*8);

  // ---- all-ones bf16 B-fragment for the denominator MFMA
  short8 ones;
#pragma unroll
  for (int i=0;i<8;i++) ones[i] = (short)0x3F80;

  f32x4 oacc[4][4];
  f32x4 oden[4];
#pragma unroll
  for (int mt=0;mt<4;mt++){ oden[mt]=(f32x4){0.f,0.f,0.f,0.f};
#pragma unroll
    for (int dt=0;dt<4;dt++) oacc[mt][dt]=(f32x4){0.f,0.f,0.f,0.f}; }

  const float LIM = 14.4269504089f;          // 10*log2(e)
  const int jbeg = half*1024, jend = jbeg+1024;
  const int prow = (wi*64 + n)*PP + wj*32;   // s_p base for this lane's rows

  for (int j0=jbeg; j0<jend; j0+=64){
    __syncthreads();                         // prev-iter s_k/s_v reads done
#pragma unroll
    for (int i=0;i<2;i++){
      const int ch = t + 256*i, row = ch>>3, lc = (ch&7)^(row&7);
      gl16(kb0 + (size_t)(j0+row)*512 + lc*8, &s_k[ch*8]);   // K rows j, k=d
      gl16(vb  + (size_t)row*L_ + j0 + lc*8,  &s_v[ch*8]);   // V rows d, k=j
    }
    __syncthreads();                         // DMA drained (vmcnt0 @ barrier)

    // ---- S^T = K*Q^T on this wave's 32 j: D[j][i], lane col=i(n), rows j
    f32x4 sacc[4][2];   // [mt][jt2]
#pragma unroll
    for (int mt=0;mt<4;mt++)
#pragma unroll
      for (int jt2=0;jt2<2;jt2++) sacc[mt][jt2]=(f32x4){0.f,0.f,0.f,0.f};
#pragma unroll
    for (int kk=0;kk<2;kk++){
      const int pc = ((kk*4+q4) ^ (n&7))*8;
      short8 aK[2];
#pragma unroll
      for (int jt2=0;jt2<2;jt2++)
        aK[jt2] = *(const short8*)&s_k[(wj*32+jt2*16+n)*64 + pc];
#pragma unroll
      for (int mt=0;mt<4;mt++)
#pragma unroll
        for (int jt2=0;jt2<2;jt2++)
          sacc[mt][jt2] = __builtin_amdgcn_mfma_f32_16x16x32_bf16(aK[jt2], qf[mt][kk], sacc[mt][jt2], 0,0,0);
    }

    // ---- p = exp2(clamp(s)); trunc-pack 4 consecutive j -> one b64 write
#pragma unroll
    for (int mt=0;mt<4;mt++)
#pragma unroll
      for (int jt2=0;jt2<2;jt2++){
        const float e0 = __builtin_amdgcn_exp2f(__builtin_amdgcn_fmed3f(sacc[mt][jt2][0],-LIM,LIM));
        const float e1 = __builtin_amdgcn_exp2f(__builtin_amdgcn_fmed3f(sacc[mt][jt2][1],-LIM,LIM));
        const float e2 = __builtin_amdgcn_exp2f(__builtin_amdgcn_fmed3f(sacc[mt][jt2][2],-LIM,LIM));
        const float e3 = __builtin_amdgcn_exp2f(__builtin_amdgcn_fmed3f(sacc[mt][jt2][3],-LIM,LIM));
        const unsigned long long pv =
            (unsigned long long)pk_tr(e0,e1) | ((unsigned long long)pk_tr(e2,e3)<<32);
        *(unsigned long long*)&s_p[prow + mt*16*PP + jt2*16 + q4*4] = pv;
      }
    // no barrier: each P cell is written & read by the same wave only

    // ---- O += P*V^T (k = this wave's 32 j); den += P*1
    {
      const int pcv = ((wj*4+q4) ^ (n&7))*8;
      short8 bV[4], pA[4];
#pragma unroll
      for (int dt=0;dt<4;dt++) bV[dt] = *(const short8*)&s_v[(dt*16+n)*64 + pcv];
#pragma unroll
      for (int mt=0;mt<4;mt++)
        pA[mt] = *(const short8*)&s_p[prow + mt*16*PP + q4*8];
#pragma unroll
      for (int mt=0;mt<4;mt++){
#pragma unroll
        for (int dt=0;dt<4;dt++)
          oacc[mt][dt] = __builtin_amdgcn_mfma_f32_16x16x32_bf16(pA[mt], bV[dt], oacc[mt][dt], 0,0,0);
        oden[mt] = __builtin_amdgcn_mfma_f32_16x16x32_bf16(pA[mt], ones, oden[mt], 0,0,0);
      }
    }
  }

  // ---- cross-wave (wj) reduction of O and den through LDS
  __syncthreads();                           // all last-iter LDS reads done
  float* ex  = (float*)smem;                 // 2 x 64 x EXP fp32
  float* dex = (float*)smem + 2*64*EXP;      // 128 fp32
  if (wj == 1){
#pragma unroll
    for (int mt=0;mt<4;mt++){
#pragma unroll
      for (int dt=0;dt<4;dt++)
#pragma unroll
        for (int r=0;r<4;r++)
          ex[(size_t)wi*64*EXP + (mt*16+q4*4+r)*EXP + dt*16+n] = oacc[mt][dt][r];
      if (n==0){
#pragma unroll
        for (int r=0;r<4;r++) dex[wi*64 + mt*16+q4*4+r] = oden[mt][r];
      }
    }
  }
  __syncthreads();
  if (wj == 0){
#pragma unroll
    for (int mt=0;mt<4;mt++){
#pragma unroll
      for (int dt=0;dt<4;dt++)
#pragma unroll
        for (int r=0;r<4;r++)
          oacc[mt][dt][r] += ex[(size_t)wi*64*EXP + (mt*16+q4*4+r)*EXP + dt*16+n];
      if (n==0){
#pragma unroll
        for (int r=0;r<4;r++)
          den[(size_t)idx*128 + wi*64 + mt*16+q4*4+r]
              = oden[mt][r] + dex[wi*64 + mt*16+q4*4+r];
      }
    }
    // ---- store unnormalized O partial bf16
#pragma unroll
    for (int mt=0;mt<4;mt++)
#pragma unroll
      for (int dt=0;dt<4;dt++)
#pragma unroll
        for (int r=0;r<4;r++)
          Opart[(size_t)idx*8192 + (wi*64 + mt*16 + q4*4 + r)*64 + dt*16 + n]
              = f2bf(oacc[mt][dt][r]);
  }
}

// ---------------------------------------------------------------------------
// Combine the two j-half partials: attnT = (O0+O1)/(d0+d1), bf16 [b][l][512].
// ---------------------------------------------------------------------------
__global__ __launch_bounds__(256) void attn_combine(
    const unsigned short* __restrict__ Opart, const float* __restrict__ den,
    unsigned short* __restrict__ attnT)
{
  __shared__ float s_inv[128];
  const int io = blockIdx.x, h = blockIdx.y, b = blockIdx.z;
  const int t = threadIdx.x;
  const int base = ((b*8+h)*16+io)*2;
  if (t < 128)
    s_inv[t] = 1.0f/(den[(size_t)base*128 + t] + den[(size_t)(base+1)*128 + t]);
  __syncthreads();
  const unsigned short* O0 = Opart + (size_t)base*8192;
  const unsigned short* O1 = O0 + 8192;
#pragma unroll
  for (int it=0; it<8; it++){
    const int chunk = it*256 + t;           // 2048 chunks of 4 elems
    const int i = chunk>>4, c4 = (chunk&15)*4;
    const us4 a = *(const us4*)&O0[i*64 + c4];
    const us4 c = *(const us4*)&O1[i*64 + c4];
    const float inv = s_inv[i];
    const us4 o = { f2bf((bf2f(a[0])+bf2f(c[0]))*inv),
                    f2bf((bf2f(a[1])+bf2f(c[1]))*inv),
                    f2bf((bf2f(a[2])+bf2f(c[2]))*inv),
                    f2bf((bf2f(a[3])+bf2f(c[3]))*inv) };
    *(us4*)&attnT[((size_t)b*L_ + io*128 + i)*512 + h*64 + c4] = o;
  }
}

// ---------------------------------------------------------------------------
// GroupNorm apply: stats come from mfma_gemm<1>'s fused atomics in part[].
// y already contains proj + bias + x. 512 blocks, quarter-group each.
// ---------------------------------------------------------------------------
__global__ __launch_bounds__(256) void gn_apply(
    const float* __restrict__ y, const float* __restrict__ part,
    const float* __restrict__ gamma, const float* __restrict__ beta,
    float* __restrict__ out)
{
  const int blk = blockIdx.x;
  const int b = blk>>7, g = (blk>>2)&31, s = blk&3;
  const float sum = part[(b*32+g)*2+0];
  const float sq  = part[(b*32+g)*2+1];
  const float mu = sum*(1.0f/32768.0f);
  const float rs = rsqrtf(sq*(1.0f/32768.0f) - mu*mu + 1e-5f);
  const size_t base = ((size_t)b*C_ + g*16)*L_ + s*512;
  const int t = threadIdx.x;
#pragma unroll
  for (int i=0;i<8;i++){
    const int e = i*256 + t;
    const int row = e>>7;
    const size_t off = base + (size_t)row*L_ + (e&127)*4;
    const int c = g*16 + row;
    const float ga = gamma[c], be = beta[c];
    const float4 vy=*(const float4*)(y+off);
    float4 r;
    r.x=(vy.x-mu)*rs*ga+be;
    r.y=(vy.y-mu)*rs*ga+be;
    r.z=(vy.z-mu)*rs*ga+be;
    r.w=(vy.w-mu)*rs*ga+be;
    *(float4*)(out+off)=r;
  }
}

// ---------------------------------------------------------------------------
extern "C" void kernel_launch(void* const* d_in, const int* in_sizes, int n_in,
                              void* d_out, int out_size, void* d_ws, size_t ws_size,
                              hipStream_t stream)
{
  (void)in_sizes; (void)n_in; (void)out_size; (void)ws_size;
  const float* x     = (const float*)d_in[0];
  const float* Wqkv  = (const float*)d_in[1];
  const float* bqkv  = (const float*)d_in[2];
  const float* Wproj = (const float*)d_in[3];
  const float* bproj = (const float*)d_in[4];
  const float* gamma = (const float*)d_in[5];
  const float* beta  = (const float*)d_in[6];
  float* out = (float*)d_out;
  char* ws = (char*)d_ws;

  const size_t MB = 1024*1024;
  unsigned short* qT    = (unsigned short*)(ws);            //  8 MB [b][l][512] (pre-scaled)
  unsigned short* kT    = (unsigned short*)(ws +  8*MB);    //  8 MB [b][l][512]
  unsigned short* vN    = (unsigned short*)(ws + 16*MB);    //  8 MB [b][512][l]
  unsigned short* attnT = (unsigned short*)(ws + 24*MB);    //  8 MB [b][l][512]
  unsigned short* xT    = (unsigned short*)(ws + 32*MB);    //  8 MB; dead after QKV gemm
  float*          den   = (float*)        (ws + 41*MB);     // 512 KB
  unsigned short* Wqb   = (unsigned short*)(ws + 42*MB);    // 1.5 MB
  unsigned short* Wpb   = (unsigned short*)(ws + 44*MB);    // 0.5 MB
  float*          y     = (float*)        (ws + 45*MB);     // 16 MB; written step 5
  unsigned short* Opart = (unsigned short*)(ws + 45*MB);    // 16 MB partials (dead before y)
  float*          part  = (float*)        (ws + 61*MB);     // 1 KB (256 floats)

  prep_k      <<<dim3(5121),   256,0,stream>>>(x, Wqkv, Wproj, xT, Wqb, Wpb, part);
  mfma_gemm<0><<<dim3(16,12,4),256,0,stream>>>(Wqb, xT,    bqkv , nullptr, qT,kT,vN, nullptr, nullptr);
  attn_v12    <<<dim3(32,8,4), 256,0,stream>>>(qT, kT, vN, Opart, den);
  attn_combine<<<dim3(16,8,4), 256,0,stream>>>(Opart, den, attnT);
  mfma_gemm<1><<<dim3(16, 4,4),256,0,stream>>>(Wpb, attnT, bproj, x, nullptr,nullptr,nullptr, y, part);
  gn_apply    <<<dim3(512),    256,0,stream>>>(y, part, gamma, beta, out);
}

// Round 11
// 186.971 us; speedup vs baseline: 1.1214x; 1.1214x over previous
//
#include <hip/hip_runtime.h>
#include <cstddef>

#define B_ 4
#define C_ 512
#define L_ 2048

typedef __attribute__((ext_vector_type(8))) short  short8;   // 8 bf16 (4 VGPRs)
typedef __attribute__((ext_vector_type(4))) float  f32x4;
typedef __attribute__((ext_vector_type(4))) unsigned short us4;

#define AS1 __attribute__((address_space(1)))
#define AS3 __attribute__((address_space(3)))

__device__ __forceinline__ float clip10(float v){ return fminf(fmaxf(v,-10.0f),10.0f); }

// round-to-nearest-even fp32 -> bf16 (finite inputs only; ours are clipped)
__device__ __forceinline__ unsigned short f2bf(float f){
  union { float f; unsigned u; } v; v.f = f;
  unsigned r = v.u + 0x7fffu + ((v.u >> 16) & 1u);
  return (unsigned short)(r >> 16);
}
// truncation-pack two fp32 -> bf16x2 in ONE v_perm_b32 (lo -> low half)
__device__ __forceinline__ unsigned pk_tr(float lo, float hi){
  return __builtin_amdgcn_perm(__float_as_uint(hi), __float_as_uint(lo), 0x07060302u);
}
__device__ __forceinline__ float bf2f(unsigned short u){
  return __uint_as_float(((unsigned)u)<<16);
}
// async 16B global -> LDS (direct-to-shared DMA)
__device__ __forceinline__ void gl16(const void* g, void* l){
  __builtin_amdgcn_global_load_lds((const AS1 unsigned*)g, (AS3 unsigned*)l, 16, 0, 0);
}

// ---------------------------------------------------------------------------
// Prep: blocks 0..4095 transpose x -> xT bf16; 4096..5119 convert W;
// block 5120 zeroes the groupnorm partial accumulators (re-poison-safe).
// ---------------------------------------------------------------------------
__global__ __launch_bounds__(256) void prep_k(
    const float* __restrict__ x, const float* __restrict__ Wq,
    const float* __restrict__ Wp, unsigned short* __restrict__ xT,
    unsigned short* __restrict__ Wqb, unsigned short* __restrict__ Wpb,
    float* __restrict__ part)
{
  const int blk = blockIdx.x;
  const int t = threadIdx.x;
  if (blk < 4096){
    __shared__ float tile[32][33];
    const int b = blk>>10, rem = blk&1023;
    const int c0 = (rem>>6)*32, l0 = (rem&63)*32;
    const int cr = t>>3, lc = (t&7)*4;
    const float4 v = *(const float4*)(x + ((size_t)b*C_ + c0+cr)*L_ + l0 + lc);
    tile[cr][lc]=v.x; tile[cr][lc+1]=v.y; tile[cr][lc+2]=v.z; tile[cr][lc+3]=v.w;
    __syncthreads();
    const int lr = t>>3, cc = (t&7)*4;
    const us4 o = { f2bf(tile[cc][lr]), f2bf(tile[cc+1][lr]),
                    f2bf(tile[cc+2][lr]), f2bf(tile[cc+3][lr]) };
    *(us4*)(xT + ((size_t)b*L_ + l0+lr)*C_ + c0 + cc) = o;
  } else if (blk < 5120){
    const int i = (blk-4096)*256 + t;       // float4 index
    const int NQ = 1536*512/4;
    const float* src; unsigned short* dst; int j;
    if (i < NQ){ src = Wq; dst = Wqb; j = i; }
    else       { src = Wp; dst = Wpb; j = i - NQ; }
    const float4 v = *(const float4*)(src + (size_t)j*4);
    const us4 o = { f2bf(v.x), f2bf(v.y), f2bf(v.z), f2bf(v.w) };
    *(us4*)(dst + (size_t)j*4) = o;
  } else {
    part[t] = 0.f;                          // 4 batches x 32 groups x {sum,sq}
  }
}

// ---------------------------------------------------------------------------
// bf16 MFMA GEMM (LDS-DMA), 128x128 tile, BK=64, K=512.
// LDS chunks XOR-swizzled: physical chunk = logical ^ (row&7).
// MODE 0 (QKV): +bias, clip; q scaled by 0.125*log2e; q/k bf16 [b][l][512];
//               v bf16 [b][512][l]. For v-blocks (mb>=8) the MFMA operands
//               are SWAPPED (D^T computed) so v stores become 8B us4 along l.
// MODE 1 (proj): +bias +x residual -> y fp32 [b][512][l]; per-group (16ch)
//               sum/sumsq wave-reduced and atomicAdd'ed into part[b][g].
// ---------------------------------------------------------------------------
template<int MODE>
__global__ __launch_bounds__(256) void mfma_gemm(
    const unsigned short* __restrict__ Wb, const unsigned short* __restrict__ Bin,
    const float* __restrict__ bias, const float* __restrict__ xres,
    unsigned short* __restrict__ qT, unsigned short* __restrict__ kT,
    unsigned short* __restrict__ vN, float* __restrict__ yout,
    float* __restrict__ part)
{
  __shared__ unsigned short SA[128*64];   // [m][k'] bf16, 16KB
  __shared__ unsigned short SB[128*64];   // [n][k'] bf16, 16KB
  const int t = threadIdx.x;
  const int b = blockIdx.z;
  const int mb = blockIdx.y, n0 = blockIdx.x*128, m0 = mb*128;
  const int lane = t&63, w = t>>6, wm = w>>1, wn = w&1;
  const int n = lane&15, q4 = lane>>4;
  const bool VSWAP = (MODE==0) && (mb>=8);

  f32x4 acc[4][4];
#pragma unroll
  for (int i=0;i<4;i++)
#pragma unroll
    for (int j=0;j<4;j++) acc[i][j] = (f32x4){0.f,0.f,0.f,0.f};

  const unsigned short* Arow = Wb + (size_t)m0*512;
  const unsigned short* Brow = Bin + ((size_t)b*L_ + n0)*512;

  for (int kt=0; kt<8; kt++){
    const int k0 = kt*64;
    __syncthreads();                     // prev-iter fragment reads done
#pragma unroll
    for (int i=0;i<4;i++){
      const int ch = t + 256*i;          // 0..1023 : row=ch>>3, phys chunk=ch&7
      const int row = ch>>3, lc = (ch&7) ^ (row&7);
      gl16(Arow + (size_t)row*512 + k0 + lc*8, &SA[ch*8]);
      gl16(Brow + (size_t)row*512 + k0 + lc*8, &SB[ch*8]);
    }
    __syncthreads();                     // vmcnt(0) drained by compiler
#pragma unroll
    for (int kk=0;kk<2;kk++){
      short8 aF[4], bF[4];
      const int pc = ((kk*4+q4) ^ (n&7))*8;
#pragma unroll
      for (int mt=0;mt<4;mt++) aF[mt] = *(const short8*)&SA[(wm*64+mt*16+n)*64 + pc];
#pragma unroll
      for (int nt=0;nt<4;nt++) bF[nt] = *(const short8*)&SB[(wn*64+nt*16+n)*64 + pc];
      if (VSWAP){
#pragma unroll
        for (int mt=0;mt<4;mt++)
#pragma unroll
          for (int nt=0;nt<4;nt++)
            acc[mt][nt] = __builtin_amdgcn_mfma_f32_16x16x32_bf16(bF[nt], aF[mt], acc[mt][nt], 0,0,0);
      } else {
#pragma unroll
        for (int mt=0;mt<4;mt++)
#pragma unroll
          for (int nt=0;nt<4;nt++)
            acc[mt][nt] = __builtin_amdgcn_mfma_f32_16x16x32_bf16(aF[mt], bF[nt], acc[mt][nt], 0,0,0);
      }
    }
  }

  const float QS = 0.180336880f;   // 0.125 * log2(e), folded into q
  if (VSWAP){
    // D^T: acc[mt][nt][r] = value at l = n0+wn*64+nt*16+q4*4+r,
    //                       c = m0+wm*64+mt*16+n  (channel 1024..1535)
#pragma unroll
    for (int mt=0;mt<4;mt++){
      const int o = m0 + wm*64 + mt*16 + n;
      const float bv = bias[o];
#pragma unroll
      for (int nt=0;nt<4;nt++){
        const int l = n0 + wn*64 + nt*16 + q4*4;
        const float r0=clip10(acc[mt][nt][0]+bv), r1=clip10(acc[mt][nt][1]+bv),
                    r2=clip10(acc[mt][nt][2]+bv), r3=clip10(acc[mt][nt][3]+bv);
        const us4 ov = { f2bf(r0), f2bf(r1), f2bf(r2), f2bf(r3) };
        *(us4*)&vN[((size_t)b*512 + (o-1024))*L_ + l] = ov;   // 8B store along l
      }
    }
    return;
  }
  // ---- normal epilogue: C row = m (quad*4+reg), col = n (lane&15)
#pragma unroll
  for (int mt=0;mt<4;mt++){
    const int obase = m0 + wm*64 + mt*16 + q4*4;
    const float b0=bias[obase], b1=bias[obase+1], b2=bias[obase+2], b3=bias[obase+3];
    float gs=0.f, gq=0.f;
#pragma unroll
    for (int nt=0;nt<4;nt++){
      const int l = n0 + wn*64 + nt*16 + n;
      float r0=acc[mt][nt][0]+b0, r1=acc[mt][nt][1]+b1,
            r2=acc[mt][nt][2]+b2, r3=acc[mt][nt][3]+b3;
      if (MODE==0){
        r0=clip10(r0); r1=clip10(r1); r2=clip10(r2); r3=clip10(r3);
        const int typ = mb>>2;                     // 0=q 1=k (v handled above)
        const int oin = obase - typ*512;
        if (typ==0){ r0*=QS; r1*=QS; r2*=QS; r3*=QS; }
        unsigned short* dst = (typ==0) ? qT : kT;
        const us4 o = { f2bf(r0), f2bf(r1), f2bf(r2), f2bf(r3) };
        *(us4*)&dst[((size_t)b*L_ + l)*512 + oin] = o;   // [l][c], 8B store
      } else {
        const float* xp = xres + ((size_t)b*512 + obase)*L_ + l;
        const float y0=r0+xp[0], y1=r1+xp[(size_t)L_],
                    y2=r2+xp[(size_t)2*L_], y3=r3+xp[(size_t)3*L_];
        float* dst = yout + ((size_t)b*512 + obase)*L_ + l;
        dst[0]=y0; dst[(size_t)L_]=y1; dst[(size_t)2*L_]=y2; dst[(size_t)3*L_]=y3;
        gs += (y0+y1)+(y2+y3);
        gq += (y0*y0+y1*y1)+(y2*y2+y3*y3);
      }
    }
    if (MODE==1){
      // whole wave belongs to one 16-channel group for this mt
#pragma unroll
      for (int off=1; off<64; off<<=1){
        gs += __shfl_xor(gs, off);
        gq += __shfl_xor(gq, off);
      }
      if (lane==0){
        const int g = mb*8 + wm*4 + mt;
        atomicAdd(&part[(b*32+g)*2+0], gs);
        atomicAdd(&part[(b*32+g)*2+1], gq);
      }
    }
  }
}

// ---------------------------------------------------------------------------
// MFMA attention v9b (= measured-best v9 + coalesced epilogue):
// 128-i tile, wave = 32 i, j-split x2 (grid 1024 = 4 blocks/CU), DMA staging,
// wave-private bf16 P, den via ones-column MFMA. Epilogue bounces O through
// the dead s_p buffer (pitch 68, wave-private rows, no barrier) so Opart
// stores become fully-coalesced 8B/lane instead of 32 scalar b16 stores.
// ---------------------------------------------------------------------------
#define PP 72   // s_p pitch in bf16: 144B rows, 16B-aligned, 2-way banks max
#define OPX 68  // epilogue bounce pitch (rows 4 apart land on disjoint banks)

__global__ __launch_bounds__(256,4) void attn_v9(
    const unsigned short* __restrict__ qT, const unsigned short* __restrict__ kT,
    const unsigned short* __restrict__ vN,
    unsigned short* __restrict__ Opart, float* __restrict__ den)
{
  __shared__ unsigned short s_k[64*64];    // [j][d] 8KB
  __shared__ unsigned short s_v[64*64];    // [d][j] 8KB
  __shared__ unsigned short s_p[128*PP];   // 18KB, wave-private rows
  const int t  = threadIdx.x;
  const int io = blockIdx.x>>1, half = blockIdx.x&1;
  const int i0 = io*128;
  const int h  = blockIdx.y, b = blockIdx.z;
  const int lane = t&63, w = t>>6, n = lane&15, q4 = lane>>4;
  const int idx = ((b*8+h)*16+io)*2 + half;

  const unsigned short* kb0 = kT + (size_t)b*L_*512 + h*64;
  const unsigned short* vb  = vN + ((size_t)b*512 + h*64)*L_;

  // ---- Q B-fragments, hoisted once from global (one-time divergence)
  short8 qf[2][2];
#pragma unroll
  for (int mt=0; mt<2; mt++)
#pragma unroll
    for (int kk=0; kk<2; kk++)
      qf[mt][kk] = *(const short8*)(qT + ((size_t)b*L_ + i0 + w*32 + mt*16 + n)*512
                                       + h*64 + kk*32 + q4*8);

  // ---- all-ones bf16 B-fragment for the denominator MFMA
  short8 ones;
#pragma unroll
  for (int i=0;i<8;i++) ones[i] = (short)0x3F80;

  f32x4 oacc[2][4];
  f32x4 oden[2];
#pragma unroll
  for (int mt=0;mt<2;mt++){ oden[mt]=(f32x4){0.f,0.f,0.f,0.f};
#pragma unroll
    for (int dt=0;dt<4;dt++) oacc[mt][dt]=(f32x4){0.f,0.f,0.f,0.f}; }

  const float LIM = 14.4269504089f;          // 10*log2(e)
  const int jbeg = half*1024, jend = jbeg+1024;

  for (int j0=jbeg; j0<jend; j0+=64){
    __syncthreads();                         // prev-iter s_k/s_v reads done
#pragma unroll
    for (int i=0;i<2;i++){
      const int ch = t + 256*i, row = ch>>3, lc = (ch&7)^(row&7);
      gl16(kb0 + (size_t)(j0+row)*512 + lc*8, &s_k[ch*8]);   // K rows j, k=d
      gl16(vb  + (size_t)row*L_ + j0 + lc*8,  &s_v[ch*8]);   // V rows d, k=j
    }
    __syncthreads();                         // DMA drained (vmcnt0 @ barrier)

    // ---- S^T = K*Q^T : D[j][i]; lane col = i (n), rows j = q4*4+r (+jt*16)
    f32x4 sacc[2][4];   // [mt][jt]
#pragma unroll
    for (int mt=0;mt<2;mt++)
#pragma unroll
      for (int jt=0;jt<4;jt++) sacc[mt][jt]=(f32x4){0.f,0.f,0.f,0.f};
#pragma unroll
    for (int kk=0;kk<2;kk++){
      const int pc = ((kk*4+q4) ^ (n&7))*8;
      short8 aK[4];
#pragma unroll
      for (int jt=0;jt<4;jt++) aK[jt] = *(const short8*)&s_k[(jt*16+n)*64 + pc];
#pragma unroll
      for (int mt=0;mt<2;mt++)
#pragma unroll
        for (int jt=0;jt<4;jt++)
          sacc[mt][jt] = __builtin_amdgcn_mfma_f32_16x16x32_bf16(aK[jt], qf[mt][kk], sacc[mt][jt], 0,0,0);
    }

    // ---- p = exp2(clamp(s)); trunc-pack 4 consecutive j -> one b64 write
#pragma unroll
    for (int mt=0;mt<2;mt++)
#pragma unroll
      for (int jt=0;jt<4;jt++){
        const float e0 = __builtin_amdgcn_exp2f(__builtin_amdgcn_fmed3f(sacc[mt][jt][0],-LIM,LIM));
        const float e1 = __builtin_amdgcn_exp2f(__builtin_amdgcn_fmed3f(sacc[mt][jt][1],-LIM,LIM));
        const float e2 = __builtin_amdgcn_exp2f(__builtin_amdgcn_fmed3f(sacc[mt][jt][2],-LIM,LIM));
        const float e3 = __builtin_amdgcn_exp2f(__builtin_amdgcn_fmed3f(sacc[mt][jt][3],-LIM,LIM));
        const unsigned long long pv =
            (unsigned long long)pk_tr(e0,e1) | ((unsigned long long)pk_tr(e2,e3)<<32);
        *(unsigned long long*)&s_p[(w*32 + mt*16 + n)*PP + jt*16 + q4*4] = pv;
      }
    // no barrier: P rows are written & read by the same wave only

    // ---- O += P*V^T ; den += P*1 (ones MFMA -> C-layout, no VALU adds)
#pragma unroll
    for (int kk=0;kk<2;kk++){
      const int pcv = ((kk*4+q4) ^ (n&7))*8;
      short8 bV[4], pA[2];
#pragma unroll
      for (int dt=0;dt<4;dt++) bV[dt] = *(const short8*)&s_v[(dt*16+n)*64 + pcv];
#pragma unroll
      for (int mt=0;mt<2;mt++)
        pA[mt] = *(const short8*)&s_p[(w*32 + mt*16 + n)*PP + kk*32 + q4*8];
#pragma unroll
      for (int mt=0;mt<2;mt++){
#pragma unroll
        for (int dt=0;dt<4;dt++)
          oacc[mt][dt] = __builtin_amdgcn_mfma_f32_16x16x32_bf16(pA[mt], bV[dt], oacc[mt][dt], 0,0,0);
        oden[mt] = __builtin_amdgcn_mfma_f32_16x16x32_bf16(pA[mt], ones, oden[mt], 0,0,0);
      }
    }
  }

  // ---- den partial: C-layout rows i = mt*16+q4*4+r, all cols identical
  if (n == 0){
#pragma unroll
    for (int mt=0;mt<2;mt++)
#pragma unroll
      for (int r=0;r<4;r++)
        den[(size_t)idx*128 + w*32 + mt*16 + q4*4 + r] = oden[mt][r];
  }

  // ---- epilogue: bounce O through s_p (wave-private rows, no barrier),
  //      then fully-coalesced 8B stores. s_p is dead after the j-loop; the
  //      same wave writes and reads only its own 32 rows.
#pragma unroll
  for (int mt=0;mt<2;mt++)
#pragma unroll
    for (int dt=0;dt<4;dt++)
#pragma unroll
      for (int r=0;r<4;r++)
        s_p[(w*32 + mt*16 + q4*4 + r)*OPX + dt*16 + n] = f2bf(oacc[mt][dt][r]);
#pragma unroll
  for (int it=0; it<8; it++){
    const int chunk = it*64 + lane;          // 512 us4 chunks for this wave
    const int row = chunk>>4, c4 = (chunk&15)*4;
    const us4 ov = *(const us4*)&s_p[(w*32 + row)*OPX + c4];
    *(us4*)&Opart[(size_t)idx*8192 + (w*32 + row)*64 + c4] = ov;
  }
}

// ---------------------------------------------------------------------------
// Combine the two j-half partials: attnT = (O0+O1)/(d0+d1), bf16 [b][l][512].
// ---------------------------------------------------------------------------
__global__ __launch_bounds__(256) void attn_combine(
    const unsigned short* __restrict__ Opart, const float* __restrict__ den,
    unsigned short* __restrict__ attnT)
{
  __shared__ float s_inv[128];
  const int io = blockIdx.x, h = blockIdx.y, b = blockIdx.z;
  const int t = threadIdx.x;
  const int base = ((b*8+h)*16+io)*2;
  if (t < 128)
    s_inv[t] = 1.0f/(den[(size_t)base*128 + t] + den[(size_t)(base+1)*128 + t]);
  __syncthreads();
  const unsigned short* O0 = Opart + (size_t)base*8192;
  const unsigned short* O1 = O0 + 8192;
#pragma unroll
  for (int it=0; it<8; it++){
    const int chunk = it*256 + t;           // 2048 chunks of 4 elems
    const int i = chunk>>4, c4 = (chunk&15)*4;
    const us4 a = *(const us4*)&O0[i*64 + c4];
    const us4 c = *(const us4*)&O1[i*64 + c4];
    const float inv = s_inv[i];
    const us4 o = { f2bf((bf2f(a[0])+bf2f(c[0]))*inv),
                    f2bf((bf2f(a[1])+bf2f(c[1]))*inv),
                    f2bf((bf2f(a[2])+bf2f(c[2]))*inv),
                    f2bf((bf2f(a[3])+bf2f(c[3]))*inv) };
    *(us4*)&attnT[((size_t)b*L_ + io*128 + i)*512 + h*64 + c4] = o;
  }
}

// ---------------------------------------------------------------------------
// GroupNorm apply: stats come from mfma_gemm<1>'s fused atomics in part[].
// y already contains proj + bias + x. 512 blocks, quarter-group each.
// ---------------------------------------------------------------------------
__global__ __launch_bounds__(256) void gn_apply(
    const float* __restrict__ y, const float* __restrict__ part,
    const float* __restrict__ gamma, const float* __restrict__ beta,
    float* __restrict__ out)
{
  const int blk = blockIdx.x;
  const int b = blk>>7, g = (blk>>2)&31, s = blk&3;
  const float sum = part[(b*32+g)*2+0];
  const float sq  = part[(b*32+g)*2+1];
  const float mu = sum*(1.0f/32768.0f);
  const float rs = rsqrtf(sq*(1.0f/32768.0f) - mu*mu + 1e-5f);
  const size_t base = ((size_t)b*C_ + g*16)*L_ + s*512;
  const int t = threadIdx.x;
#pragma unroll
  for (int i=0;i<8;i++){
    const int e = i*256 + t;
    const int row = e>>7;
    const size_t off = base + (size_t)row*L_ + (e&127)*4;
    const int c = g*16 + row;
    const float ga = gamma[c], be = beta[c];
    const float4 vy=*(const float4*)(y+off);
    float4 r;
    r.x=(vy.x-mu)*rs*ga+be;
    r.y=(vy.y-mu)*rs*ga+be;
    r.z=(vy.z-mu)*rs*ga+be;
    r.w=(vy.w-mu)*rs*ga+be;
    *(float4*)(out+off)=r;
  }
}

// ---------------------------------------------------------------------------
extern "C" void kernel_launch(void* const* d_in, const int* in_sizes, int n_in,
                              void* d_out, int out_size, void* d_ws, size_t ws_size,
                              hipStream_t stream)
{
  (void)in_sizes; (void)n_in; (void)out_size; (void)ws_size;
  const float* x     = (const float*)d_in[0];
  const float* Wqkv  = (const float*)d_in[1];
  const float* bqkv  = (const float*)d_in[2];
  const float* Wproj = (const float*)d_in[3];
  const float* bproj = (const float*)d_in[4];
  const float* gamma = (const float*)d_in[5];
  const float* beta  = (const float*)d_in[6];
  float* out = (float*)d_out;
  char* ws = (char*)d_ws;

  const size_t MB = 1024*1024;
  unsigned short* qT    = (unsigned short*)(ws);            //  8 MB [b][l][512] (pre-scaled)
  unsigned short* kT    = (unsigned short*)(ws +  8*MB);    //  8 MB [b][l][512]
  unsigned short* vN    = (unsigned short*)(ws + 16*MB);    //  8 MB [b][512][l]
  unsigned short* attnT = (unsigned short*)(ws + 24*MB);    //  8 MB [b][l][512]
  unsigned short* xT    = (unsigned short*)(ws + 32*MB);    //  8 MB; dead after QKV gemm
  float*          den   = (float*)        (ws + 41*MB);     // 512 KB
  unsigned short* Wqb   = (unsigned short*)(ws + 42*MB);    // 1.5 MB
  unsigned short* Wpb   = (unsigned short*)(ws + 44*MB);    // 0.5 MB
  float*          y     = (float*)        (ws + 45*MB);     // 16 MB; written step 5
  unsigned short* Opart = (unsigned short*)(ws + 45*MB);    // 16 MB partials (dead before y)
  float*          part  = (float*)        (ws + 61*MB);     // 1 KB (256 floats)

  prep_k      <<<dim3(5121),   256,0,stream>>>(x, Wqkv, Wproj, xT, Wqb, Wpb, part);
  mfma_gemm<0><<<dim3(16,12,4),256,0,stream>>>(Wqb, xT,    bqkv , nullptr, qT,kT,vN, nullptr, nullptr);
  attn_v9     <<<dim3(32,8,4), 256,0,stream>>>(qT, kT, vN, Opart, den);
  attn_combine<<<dim3(16,8,4), 256,0,stream>>>(Opart, den, attnT);
  mfma_gemm<1><<<dim3(16, 4,4),256,0,stream>>>(Wpb, attnT, bproj, x, nullptr,nullptr,nullptr, y, part);
  gn_apply    <<<dim3(512),    256,0,stream>>>(y, part, gamma, beta, out);
}